// Round 6
// baseline (1422.472 us; speedup 1.0000x reference)
//
#include <hip/hip_runtime.h>
#include <math.h>

#define DEVI __device__ __forceinline__
typedef unsigned short u16;
typedef unsigned int u32;
typedef __bf16 bf16x8 __attribute__((ext_vector_type(8)));
typedef float f32x4 __attribute__((ext_vector_type(4)));

static constexpr int CAP = 8192;   // per (router,rank,expert) list capacity

DEVI u16 f2b(float f) {            // f32 -> bf16 bits, RNE
  u32 x = __builtin_bit_cast(u32, f);
  u32 r = (x + 0x7fffu + ((x >> 16) & 1u)) >> 16;
  return (u16)r;
}
DEVI float b2f(u16 u) { return __builtin_bit_cast(float, (u32)u << 16); }

DEVI void async16(const u16* g, u16* l) {
  __builtin_amdgcn_global_load_lds((__attribute__((address_space(1))) void*)g,
                                   (__attribute__((address_space(3))) void*)l, 16, 0, 0);
}

// ---------------- f32 -> bf16 conversion ----------------
__global__ void cvt_k(const float* __restrict__ s0, u16* __restrict__ d0, long n0) {
  long nq = n0 / 4;
  long stride = (long)gridDim.x * blockDim.x;
  for (long q = (long)blockIdx.x * blockDim.x + threadIdx.x; q < nq; q += stride) {
    float4 v = ((const float4*)s0)[q];
    ushort4 o;
    o.x = f2b(v.x); o.y = f2b(v.y); o.z = f2b(v.z); o.w = f2b(v.w);
    ((ushort4*)d0)[q] = o;
  }
}

// ---------------- fused router: 8 tokens/block, 1024 blocks ----------------
__global__ __launch_bounds__(256) void xrouter_k(
    const float* __restrict__ x, const float* __restrict__ Pw,
    const float* __restrict__ U1, const float* __restrict__ U2, const float* __restrict__ U3,
    const float* __restrict__ b2,
    int* __restrict__ cnt, int* __restrict__ ltok, float* __restrict__ lwgt,
    float* __restrict__ out, u16* __restrict__ xb) {
  __shared__ __align__(16) char sm[22400];
  float*  xs  = (float*)sm;                    // [8][68]  f32
  float*  pws = (float*)(sm + 2176);           // [64][68] f32   (stage A)
  float*  us  = (float*)(sm + 2176);           // [36][68] f32   (stage B, alias)
  double* xa  = (double*)(sm + 11968);         // [8][66]  f64   (stage B, alias)
  double* zz  = (double*)(sm + 19584);         // [8][40]  f64
  int*    se  = (int*)(sm + 22144);            // [8][4]
  float*  swg = (float*)(sm + 22272);          // [8][4]

  const int tid = threadIdx.x;
  const int tok0 = blockIdx.x * 8;
  const int tok = tid >> 5, dg = tid & 31;

  double a0 = 0, a1 = 0, a2 = 0, a3 = 0;

  for (int kc = 0; kc < 16; ++kc) {
    if (tid < 128) {
      int t = tid >> 4, c4 = tid & 15;
      size_t goff = (size_t)(tok0 + t) * 1024 + kc * 64 + c4 * 4;
      float4 v = *(const float4*)&x[goff];
      *(float4*)&xs[t * 68 + c4 * 4] = v;
      ushort4 o; o.x = f2b(v.x); o.y = f2b(v.y); o.z = f2b(v.z); o.w = f2b(v.w);
      *(ushort4*)&xb[goff] = o;
    }
#pragma unroll
    for (int j = 0; j < 4; ++j) {
      int f = tid + 256 * j;
      int r = f >> 4, c4 = f & 15;
      *(float4*)&pws[r * 68 + c4 * 4] = *(const float4*)&Pw[(size_t)r * 1024 + kc * 64 + c4 * 4];
    }
    __syncthreads();
    const float* xrow = &xs[tok * 68];
    const float* p0 = &pws[dg * 68];
    const float* p1 = &pws[(dg + 32) * 68];
#pragma unroll
    for (int k4 = 0; k4 < 16; ++k4) {
      float4 xv = *(const float4*)&xrow[k4 * 4];
      float4 q0 = *(const float4*)&p0[k4 * 4];
      float4 q1 = *(const float4*)&p1[k4 * 4];
      a0 += (double)xv.x * q0.x + (double)xv.y * q0.y;
      a1 += (double)xv.z * q0.z + (double)xv.w * q0.w;
      a2 += (double)xv.x * q1.x + (double)xv.y * q1.y;
      a3 += (double)xv.z * q1.z + (double)xv.w * q1.w;
    }
    __syncthreads();
  }

  xa[tok * 66 + dg] = a0 + a1;
  xa[tok * 66 + dg + 32] = a2 + a3;
  if (tid < 144) {
#pragma unroll
    for (int j = 0; j < 4; ++j) {
      int f = tid * 4 + j;
      int r = f >> 4, c4 = f & 15;
      const float* U = (r < 12) ? (U1 + r * 64) : (r < 24 ? U2 + (r - 12) * 64 : U3 + (r - 24) * 64);
      *(float4*)&us[r * 68 + c4 * 4] = *(const float4*)&U[c4 * 4];
    }
  }
  __syncthreads();

#pragma unroll
  for (int rep = 0; rep < 2; ++rep) {
    int idx = tid + 256 * rep;
    int tk = idx >> 6, re = idx & 63;
    if (re < 36) {
      double acc = 0;
      const double* xr = &xa[tk * 66];
      const float* ur = &us[re * 68];
      for (int k = 0; k < 64; ++k) acc += xr[k] * (double)ur[k];
      zz[tk * 40 + re] = acc;
    }
  }
  __syncthreads();

  if (tid < 24) {
    const int tk = tid & 7, r = tid >> 3;
    const double* z = &zz[tk * 40 + r * 12];
    double v0 = -1e300, v1 = -1e300, v2 = -1e300;
    int i0 = 0, i1 = 0, i2 = 0;
    for (int e = 0; e < 12; ++e) {
      double v = z[e];
      if (v > v0)      { v2 = v1; i2 = i1; v1 = v0; i1 = i0; v0 = v; i0 = e; }
      else if (v > v1) { v2 = v1; i2 = i1; v1 = v; i1 = e; }
      else if (v > v2) { v2 = v; i2 = e; }
    }
    const double inv_tau = 1.0 / (1.0 + 1e-8);
    double e1 = exp((v1 - v0) * inv_tau), e2 = exp((v2 - v0) * inv_tau);
    double s = 1.0 / (1.0 + e1 + e2);
    double w0 = s, w1 = e1 * s, w2 = e2 * s;
    int n = tok0 + tk;
    if (r < 2) {
      int jj3[3] = { i0, i1, i2 };
      double ww[3] = { w0, w1, w2 };
      for (int j = 0; j < 3; ++j) {
        int slot = (r * 3 + j) * 12 + jj3[j];
        int pos = atomicAdd(&cnt[slot], 1);
        ltok[slot * CAP + pos] = n;
        lwgt[slot * CAP + pos] = (float)ww[j];
      }
    } else {
      se[tk * 4 + 0] = i0; se[tk * 4 + 1] = i1; se[tk * 4 + 2] = i2;
      swg[tk * 4 + 0] = (float)w0; swg[tk * 4 + 1] = (float)w1; swg[tk * 4 + 2] = (float)w2;
    }
  }
  __syncthreads();

#pragma unroll
  for (int j = 0; j < 8; ++j) {
    int f = tid + 256 * j;
    int tk = f >> 8, c4 = f & 255;
    const float w0 = swg[tk * 4 + 0], w1 = swg[tk * 4 + 1], w2 = swg[tk * 4 + 2];
    float4 a = *(const float4*)&b2[(size_t)se[tk * 4 + 0] * 1024 + c4 * 4];
    float4 b = *(const float4*)&b2[(size_t)se[tk * 4 + 1] * 1024 + c4 * 4];
    float4 d = *(const float4*)&b2[(size_t)se[tk * 4 + 2] * 1024 + c4 * 4];
    float4 o;
    o.x = w0 * a.x + w1 * b.x + w2 * d.x;
    o.y = w0 * a.y + w1 * b.y + w2 * d.y;
    o.z = w0 * a.z + w1 * b.z + w2 * d.z;
    o.w = w0 * a.w + w1 * b.w + w2 * d.w;
    *(float4*)&out[(size_t)(tok0 + tk) * 1024 + c4 * 4] = o;
  }
}

// ---------------- tile descriptor build (256-row tiles) ----------------
__global__ void build_k(const int* __restrict__ cnt, int2* __restrict__ desc,
                        int* __restrict__ ntl) {
  int t = threadIdx.x;
  if (t < 6) {
    int nt = 0;
    for (int e = 0; e < 12; ++e) {
      int c = cnt[t * 12 + e];
      for (int s = 0; s < c; s += 256) { desc[t * 48 + nt] = make_int2(e, s); ++nt; }
    }
    ntl[t] = nt;
  }
}

// ---------------- grouped GEMM: 256x256, BK=32, 4-buf deep pipeline ----------------
// T1 XCD swizzle + T2 LDS swizzle + T3/T4 counted-vmcnt 3-ahead prefetch + T5 setprio.
// CT = u16 (bf16 RMW, used for h) or float (f32 RMW, used for d_out)
template<int K, int NOUT, bool ADD, typename CT>
__global__ __launch_bounds__(512, 1) void moe_gemm(
    const u16* __restrict__ A, const u16* __restrict__ W, CT* __restrict__ C,
    const int* __restrict__ cnt12, const int* __restrict__ ltok12,
    const float* __restrict__ lwgt12,
    const int2* __restrict__ desc, const int* __restrict__ ntl) {
  // T1: XCD-chunked swizzle (nwg % 8 == 0 for both grids used)
  unsigned lin = blockIdx.y * gridDim.x + blockIdx.x;
  unsigned q = (gridDim.x * gridDim.y) >> 3;
  unsigned swz = (lin & 7) * q + (lin >> 3);
  int tile = swz % gridDim.x;
  int ntile = swz / gridDim.x;
  if (tile >= *ntl) return;
  const int2 dd = desc[tile];
  const int e = dd.x, rowStart = dd.y;
  const int rows = min(256, cnt12[e] - rowStart);
  const int base = e * CAP + rowStart;

  __shared__ __align__(16) u16 As[4][8192];   // 4 bufs x 256 x 32
  __shared__ __align__(16) u16 Bs[4][8192];   // 128 KB total
  __shared__ int tokL[256];
  __shared__ float wgtL[256];

  const int tid = threadIdx.x;
  const int lane = tid & 63, w = tid >> 6;
  if (tid < 256) {
    int li = min(tid, rows - 1);
    tokL[tid] = ltok12[base + li];
    wgtL[tid] = lwgt12[base + li];
  }
  __syncthreads();

  // T2 staging: linear LDS dest slot s=i*512+tid -> (row=i*128+(tid>>2), col16=tid&3);
  // source column pre-swizzled: col16 ^ ((row>>1)&3)
  const int srcOff = (((tid & 3) ^ ((tid >> 3) & 3)) * 8);
  const u16* aSrc[2]; const u16* bSrc[2];
#pragma unroll
  for (int i = 0; i < 2; ++i) {
    int r = i * 128 + (tid >> 2);
    aSrc[i] = A + (size_t)tokL[min(r, rows - 1)] * K + srcOff;
    bSrc[i] = W + ((size_t)e * NOUT + ntile * 256 + r) * K + srcOff;
  }

  f32x4 acc[8][4] = {};
  const int wr = w >> 2, wc = w & 3;            // 2 x 4 wave grid
  // read-side swizzle: want k-slot g=(lane>>4); stored at col16 g^((row>>1)&3), row&6 -> (lane>>1)&3
  const int rdOff = (((lane >> 4) ^ ((lane >> 1) & 3)) * 8);
  constexpr int NT = K / 32;

#define STAGE(kt_) do { int koff_ = (kt_) * 32; int bu_ = (kt_) & 3;            \
    _Pragma("unroll") for (int i_ = 0; i_ < 2; ++i_) {                          \
      int s_ = i_ * 512 + tid;                                                  \
      async16(aSrc[i_] + koff_, &As[bu_][s_ * 8]);                              \
      async16(bSrc[i_] + koff_, &Bs[bu_][s_ * 8]); } } while (0)

  // prologue: 3 stages in flight (12 per-thread loads)
  STAGE(0); STAGE(1); STAGE(2);

  for (int kt = 0; kt < NT; ++kt) {
    // counted vmcnt: wait for stage kt only; stages kt+1,kt+2 stay in flight
    if (kt < NT - 2)       asm volatile("s_waitcnt vmcnt(8)" ::: "memory");
    else if (kt == NT - 2) asm volatile("s_waitcnt vmcnt(4)" ::: "memory");
    else                   asm volatile("s_waitcnt vmcnt(0)" ::: "memory");
    __builtin_amdgcn_s_barrier();   // single barrier per K-step: protects buf (kt+3)&3 reuse
    if (kt + 3 < NT) STAGE(kt + 3);

    const u16* Ab = &As[kt & 3][0];
    const u16* Bb = &Bs[kt & 3][0];
    bf16x8 bfr[4];
#pragma unroll
    for (int ni = 0; ni < 4; ++ni) {
      int rB = wc * 64 + ni * 16 + (lane & 15);
      bfr[ni] = *(const bf16x8*)&Bb[rB * 32 + rdOff];
    }
    bf16x8 af[8];
#pragma unroll
    for (int mi = 0; mi < 8; ++mi) {
      int rA = wr * 128 + mi * 16 + (lane & 15);
      af[mi] = *(const bf16x8*)&Ab[rA * 32 + rdOff];
    }
    __builtin_amdgcn_s_setprio(1);
#pragma unroll
    for (int mi = 0; mi < 8; ++mi)
#pragma unroll
      for (int ni = 0; ni < 4; ++ni)
        acc[mi][ni] = __builtin_amdgcn_mfma_f32_16x16x32_bf16(af[mi], bfr[ni], acc[mi][ni], 0, 0, 0);
    __builtin_amdgcn_s_setprio(0);
  }
#undef STAGE

  // epilogue: scaled scatter (RMW; bf16 pair-packed u32, f32 scalar)
#pragma unroll
  for (int mi = 0; mi < 8; ++mi) {
    int lr0 = wr * 128 + mi * 16 + ((lane >> 4) << 2);
#pragma unroll
    for (int rr = 0; rr < 4; ++rr) {
      int lrow = lr0 + rr;
      bool rowok = lrow < rows;
      int tok = tokL[lrow];
      float wv = wgtL[lrow];
      if constexpr (sizeof(CT) == 2) {
        u32* cp32 = (u32*)((u16*)C + (size_t)tok * NOUT + ntile * 256 + wc * 64 + (lane & 14));
#pragma unroll
        for (int ni = 0; ni < 4; ++ni) {
          float v = acc[mi][ni][rr] * wv;
          float vo = __shfl_xor(v, 1);
          if (rowok && !(lane & 1)) {
            float lo = v, hi = vo;
            if (ADD) {
              u32 curv = cp32[ni * 8];
              lo += b2f((u16)(curv & 0xffffu));
              hi += b2f((u16)(curv >> 16));
            }
            cp32[ni * 8] = (u32)f2b(lo) | ((u32)f2b(hi) << 16);
          }
        }
      } else {
        if (rowok) {
          float* cp = (float*)C + (size_t)tok * NOUT + ntile * 256 + wc * 64 + (lane & 15);
#pragma unroll
          for (int ni = 0; ni < 4; ++ni) {
            float val = acc[mi][ni][rr] * wv;
            float* p = cp + ni * 16;
            *p = ADD ? (*p + val) : val;
          }
        }
      }
    }
  }
}

// ---------------- exact GELU in-place on bf16 h ----------------
DEVI float gelu1(float v) { return 0.5f * v * (1.0f + erff(v * 0.70710678118654752f)); }
DEVI u32 gpair(u32 u) {
  float lo = __builtin_bit_cast(float, (u & 0xffffu) << 16);
  float hi = __builtin_bit_cast(float, u & 0xffff0000u);
  return (u32)f2b(gelu1(lo)) | ((u32)f2b(gelu1(hi)) << 16);
}
__global__ void gelu_k(u32* __restrict__ h, long n4) {
  long stride = (long)gridDim.x * blockDim.x;
  uint4* p = (uint4*)h;
  for (long i = (long)blockIdx.x * blockDim.x + threadIdx.x; i < n4; i += stride) {
    uint4 v = p[i];
    v.x = gpair(v.x); v.y = gpair(v.y); v.z = gpair(v.z); v.w = gpair(v.w);
    p[i] = v;
  }
}

extern "C" void kernel_launch(void* const* d_in, const int* in_sizes, int n_in,
                              void* d_out, int out_size, void* d_ws, size_t ws_size,
                              hipStream_t stream) {
  const float* x  = (const float*)d_in[0];
  const float* Pw = (const float*)d_in[1];
  const float* U1 = (const float*)d_in[2];
  const float* U2 = (const float*)d_in[3];
  const float* U3 = (const float*)d_in[4];
  const float* W1 = (const float*)d_in[5];
  const float* W2 = (const float*)d_in[6];
  const float* b2 = (const float*)d_in[7];
  float* out = (float*)d_out;

  char* ws = (char*)d_ws;
  size_t o = 0;
  u16* Wb = (u16*)(ws + o); o += (size_t)12 * 4096 * 1024 * 2;  // W1b, later W2b
  u16* xb = (u16*)(ws + o); o += (size_t)8192 * 1024 * 2;
  u16* h  = (u16*)(ws + o); o += (size_t)8192 * 4096 * 2;
  int* cnt = (int*)(ws + o); o += 512;
  int2* desc = (int2*)(ws + o); o += (size_t)6 * 48 * sizeof(int2);
  o = (o + 255) & ~(size_t)255;
  int* ntl = (int*)(ws + o); o += 256;
  int* ltok = (int*)(ws + o); o += (size_t)6 * 12 * CAP * 4;
  float* lwgt = (float*)(ws + o); o += (size_t)6 * 12 * CAP * 4;
  if (ws_size < o) return;

  hipMemsetAsync(cnt, 0, 512, stream);
  cvt_k<<<4096, 256, 0, stream>>>(W1, Wb, (long)12 * 4096 * 1024);
  xrouter_k<<<1024, 256, 0, stream>>>(x, Pw, U1, U2, U3, b2, cnt, ltok, lwgt, out, xb);
  build_k<<<1, 64, 0, stream>>>(cnt, desc, ntl);

  { // layer 1: h = sum over ranks of w * (x @ W1[e]^T)   (bf16 RMW in ws)
    dim3 g(48, 16);
    int s;
    s = 0; moe_gemm<1024, 4096, false, u16><<<g, 512, 0, stream>>>(xb, Wb, h, cnt + s * 12, ltok + (size_t)s * 12 * CAP, lwgt + (size_t)s * 12 * CAP, desc + s * 48, ntl + s);
    s = 1; moe_gemm<1024, 4096, true , u16><<<g, 512, 0, stream>>>(xb, Wb, h, cnt + s * 12, ltok + (size_t)s * 12 * CAP, lwgt + (size_t)s * 12 * CAP, desc + s * 48, ntl + s);
    s = 2; moe_gemm<1024, 4096, true , u16><<<g, 512, 0, stream>>>(xb, Wb, h, cnt + s * 12, ltok + (size_t)s * 12 * CAP, lwgt + (size_t)s * 12 * CAP, desc + s * 48, ntl + s);
  }

  cvt_k<<<4096, 256, 0, stream>>>(W2, Wb, (long)12 * 1024 * 4096);
  gelu_k<<<2048, 256, 0, stream>>>((u32*)h, (long)8192 * 4096 / 8);

  { // layer 2: out += sum over ranks of w * (gelu(h) @ W2[e]^T)   (bias already in out, f32)
    dim3 g(48, 4);
    int s;
    s = 3; moe_gemm<4096, 1024, true, float><<<g, 512, 0, stream>>>(h, Wb, out, cnt + s * 12, ltok + (size_t)s * 12 * CAP, lwgt + (size_t)s * 12 * CAP, desc + s * 48, ntl + s);
    s = 4; moe_gemm<4096, 1024, true, float><<<g, 512, 0, stream>>>(h, Wb, out, cnt + s * 12, ltok + (size_t)s * 12 * CAP, lwgt + (size_t)s * 12 * CAP, desc + s * 48, ntl + s);
    s = 5; moe_gemm<4096, 1024, true, float><<<g, 512, 0, stream>>>(h, Wb, out, cnt + s * 12, ltok + (size_t)s * 12 * CAP, lwgt + (size_t)s * 12 * CAP, desc + s * 48, ntl + s);
  }
}

// Round 7
// 856.747 us; speedup vs baseline: 1.6603x; 1.6603x over previous
//
#include <hip/hip_runtime.h>
#include <math.h>

#define DEVI __device__ __forceinline__
typedef unsigned short u16;
typedef unsigned int u32;
typedef unsigned char u8;
typedef float f32x4 __attribute__((ext_vector_type(4)));

static constexpr int CAP = 8192;   // per (router,rank,expert) list capacity

DEVI u16 f2b(float f) {            // f32 -> bf16 bits, RNE
  u32 x = __builtin_bit_cast(u32, f);
  u32 r = (x + 0x7fffu + ((x >> 16) & 1u)) >> 16;
  return (u16)r;
}
DEVI float b2f(u16 u) { return __builtin_bit_cast(float, (u32)u << 16); }

DEVI u32 f2fp8(float f) {          // f32 -> OCP e4m3fn, RNE, saturating
  u32 x = __builtin_bit_cast(u32, f);
  u32 s = (x >> 24) & 0x80u;
  u32 ax = x & 0x7fffffffu;
  if (ax >= 0x43e80000u) return s | 0x7eu;           // >=464 -> +-448
  if (ax < 0x3a800000u) return s;                    // < 2^-10 -> 0
  if (ax < 0x3c800000u) {                            // subnormal: step 2^-9
    float m = __builtin_bit_cast(float, ax) * 512.0f;
    return s | (u32)rintf(m);                        // 8 -> 0x08 = 2^-6 (ok)
  }
  u32 r = ax + 0x7ffffu + ((ax >> 20) & 1u);         // RNE at bit 20
  return s | (((r >> 23) - 120u) << 3) | ((r >> 20) & 7u);
}

DEVI void async16(const void* g, void* l) {
  __builtin_amdgcn_global_load_lds((const __attribute__((address_space(1))) void*)g,
                                   (__attribute__((address_space(3))) void*)l, 16, 0, 0);
}

// ---------------- f32 -> fp8(x1024) conversion of W1 and W2 ----------------
__global__ void cvt8_k(const float* __restrict__ s0, u8* __restrict__ d0,
                       const float* __restrict__ s1, u8* __restrict__ d1, long n) {
  long nq0 = n / 4, nq = nq0 * 2;
  long stride = (long)gridDim.x * blockDim.x;
  for (long q = (long)blockIdx.x * blockDim.x + threadIdx.x; q < nq; q += stride) {
    long qi = q; const float* s = s0; u8* d = d0;
    if (qi >= nq0) { qi -= nq0; s = s1; d = d1; }
    float4 v = ((const float4*)s)[qi];
    uchar4 o;
    o.x = (u8)f2fp8(v.x * 1024.f); o.y = (u8)f2fp8(v.y * 1024.f);
    o.z = (u8)f2fp8(v.z * 1024.f); o.w = (u8)f2fp8(v.w * 1024.f);
    ((uchar4*)d)[qi] = o;
  }
}

// ---------------- fused router: 8 tokens/block, 1024 blocks ----------------
// Emits xb as fp8 (unscaled), bias-init of out (f32), routing lists.
__global__ __launch_bounds__(256) void xrouter_k(
    const float* __restrict__ x, const float* __restrict__ Pw,
    const float* __restrict__ U1, const float* __restrict__ U2, const float* __restrict__ U3,
    const float* __restrict__ b2,
    int* __restrict__ cnt, int* __restrict__ ltok, float* __restrict__ lwgt,
    float* __restrict__ out, u8* __restrict__ xb) {
  __shared__ __align__(16) char sm[22400];
  float*  xs  = (float*)sm;                    // [8][68]  f32
  float*  pws = (float*)(sm + 2176);           // [64][68] f32   (stage A)
  float*  us  = (float*)(sm + 2176);           // [36][68] f32   (stage B, alias)
  double* xa  = (double*)(sm + 11968);         // [8][66]  f64   (stage B, alias)
  double* zz  = (double*)(sm + 19584);         // [8][40]  f64
  int*    se  = (int*)(sm + 22144);            // [8][4]
  float*  swg = (float*)(sm + 22272);          // [8][4]

  const int tid = threadIdx.x;
  const int tok0 = blockIdx.x * 8;
  const int tok = tid >> 5, dg = tid & 31;

  double a0 = 0, a1 = 0, a2 = 0, a3 = 0;

  for (int kc = 0; kc < 16; ++kc) {
    if (tid < 128) {
      int t = tid >> 4, c4 = tid & 15;
      size_t goff = (size_t)(tok0 + t) * 1024 + kc * 64 + c4 * 4;
      float4 v = *(const float4*)&x[goff];
      *(float4*)&xs[t * 68 + c4 * 4] = v;
      uchar4 o;
      o.x = (u8)f2fp8(v.x); o.y = (u8)f2fp8(v.y);
      o.z = (u8)f2fp8(v.z); o.w = (u8)f2fp8(v.w);
      *(uchar4*)&xb[goff] = o;
    }
#pragma unroll
    for (int j = 0; j < 4; ++j) {
      int f = tid + 256 * j;
      int r = f >> 4, c4 = f & 15;
      *(float4*)&pws[r * 68 + c4 * 4] = *(const float4*)&Pw[(size_t)r * 1024 + kc * 64 + c4 * 4];
    }
    __syncthreads();
    const float* xrow = &xs[tok * 68];
    const float* p0 = &pws[dg * 68];
    const float* p1 = &pws[(dg + 32) * 68];
#pragma unroll
    for (int k4 = 0; k4 < 16; ++k4) {
      float4 xv = *(const float4*)&xrow[k4 * 4];
      float4 q0 = *(const float4*)&p0[k4 * 4];
      float4 q1 = *(const float4*)&p1[k4 * 4];
      a0 += (double)xv.x * q0.x + (double)xv.y * q0.y;
      a1 += (double)xv.z * q0.z + (double)xv.w * q0.w;
      a2 += (double)xv.x * q1.x + (double)xv.y * q1.y;
      a3 += (double)xv.z * q1.z + (double)xv.w * q1.w;
    }
    __syncthreads();
  }

  xa[tok * 66 + dg] = a0 + a1;
  xa[tok * 66 + dg + 32] = a2 + a3;
  if (tid < 144) {
#pragma unroll
    for (int j = 0; j < 4; ++j) {
      int f = tid * 4 + j;
      int r = f >> 4, c4 = f & 15;
      const float* U = (r < 12) ? (U1 + r * 64) : (r < 24 ? U2 + (r - 12) * 64 : U3 + (r - 24) * 64);
      *(float4*)&us[r * 68 + c4 * 4] = *(const float4*)&U[c4 * 4];
    }
  }
  __syncthreads();

#pragma unroll
  for (int rep = 0; rep < 2; ++rep) {
    int idx = tid + 256 * rep;
    int tk = idx >> 6, re = idx & 63;
    if (re < 36) {
      double acc = 0;
      const double* xr = &xa[tk * 66];
      const float* ur = &us[re * 68];
      for (int k = 0; k < 64; ++k) acc += xr[k] * (double)ur[k];
      zz[tk * 40 + re] = acc;
    }
  }
  __syncthreads();

  if (tid < 24) {
    const int tk = tid & 7, r = tid >> 3;
    const double* z = &zz[tk * 40 + r * 12];
    double v0 = -1e300, v1 = -1e300, v2 = -1e300;
    int i0 = 0, i1 = 0, i2 = 0;
    for (int e = 0; e < 12; ++e) {
      double v = z[e];
      if (v > v0)      { v2 = v1; i2 = i1; v1 = v0; i1 = i0; v0 = v; i0 = e; }
      else if (v > v1) { v2 = v1; i2 = i1; v1 = v; i1 = e; }
      else if (v > v2) { v2 = v; i2 = e; }
    }
    const double inv_tau = 1.0 / (1.0 + 1e-8);
    double e1 = exp((v1 - v0) * inv_tau), e2 = exp((v2 - v0) * inv_tau);
    double s = 1.0 / (1.0 + e1 + e2);
    double w0 = s, w1 = e1 * s, w2 = e2 * s;
    int n = tok0 + tk;
    if (r < 2) {
      int jj3[3] = { i0, i1, i2 };
      double ww[3] = { w0, w1, w2 };
      for (int j = 0; j < 3; ++j) {
        int slot = (r * 3 + j) * 12 + jj3[j];
        int pos = atomicAdd(&cnt[slot], 1);
        ltok[slot * CAP + pos] = n;
        lwgt[slot * CAP + pos] = (float)ww[j];
      }
    } else {
      se[tk * 4 + 0] = i0; se[tk * 4 + 1] = i1; se[tk * 4 + 2] = i2;
      swg[tk * 4 + 0] = (float)w0; swg[tk * 4 + 1] = (float)w1; swg[tk * 4 + 2] = (float)w2;
    }
  }
  __syncthreads();

#pragma unroll
  for (int j = 0; j < 8; ++j) {
    int f = tid + 256 * j;
    int tk = f >> 8, c4 = f & 255;
    const float w0 = swg[tk * 4 + 0], w1 = swg[tk * 4 + 1], w2 = swg[tk * 4 + 2];
    float4 a = *(const float4*)&b2[(size_t)se[tk * 4 + 0] * 1024 + c4 * 4];
    float4 b = *(const float4*)&b2[(size_t)se[tk * 4 + 1] * 1024 + c4 * 4];
    float4 d = *(const float4*)&b2[(size_t)se[tk * 4 + 2] * 1024 + c4 * 4];
    float4 o;
    o.x = w0 * a.x + w1 * b.x + w2 * d.x;
    o.y = w0 * a.y + w1 * b.y + w2 * d.y;
    o.z = w0 * a.z + w1 * b.z + w2 * d.z;
    o.w = w0 * a.w + w1 * b.w + w2 * d.w;
    *(float4*)&out[(size_t)(tok0 + tk) * 1024 + c4 * 4] = o;
  }
}

// ---------------- tile descriptor build (128-row tiles) ----------------
__global__ void build_k(const int* __restrict__ cnt, int2* __restrict__ desc,
                        int* __restrict__ ntl) {
  int t = threadIdx.x;
  if (t < 6) {
    int nt = 0;
    for (int e = 0; e < 12; ++e) {
      int c = cnt[t * 12 + e];
      for (int s = 0; s < c; s += 128) { desc[t * 96 + nt] = make_int2(e, s); ++nt; }
    }
    ntl[t] = nt;
  }
}

// ---------------- grouped GEMM: fp8, 128x128 tile, BK=64, 2-buf, 4 blocks/CU ----------------
// KB = K in bytes (== elements, fp8). CT = u16 (bf16 RMW for h) or float (f32 RMW for out).
template<int KB, int NOUT, bool ADD, typename CT>
__global__ __launch_bounds__(256, 4) void moe_gemm(
    const u8* __restrict__ A, const u8* __restrict__ W, CT* __restrict__ C,
    float outScale,
    const int* __restrict__ cnt12, const int* __restrict__ ltok12,
    const float* __restrict__ lwgt12,
    const int2* __restrict__ desc, const int* __restrict__ ntl) {
  // T1: XCD-chunked swizzle (grid products are %8==0)
  unsigned lin = blockIdx.y * gridDim.x + blockIdx.x;
  unsigned q = (gridDim.x * gridDim.y) >> 3;
  unsigned swz = (lin & 7) * q + (lin >> 3);
  int tile = swz % gridDim.x;
  int ntile = swz / gridDim.x;
  if (tile >= *ntl) return;
  const int2 dd = desc[tile];
  const int e = dd.x, rowStart = dd.y;
  const int rows = min(128, cnt12[e] - rowStart);
  const int base = e * CAP + rowStart;

  __shared__ __align__(16) u8 As[2][8192];   // 2 x 128 x 64
  __shared__ __align__(16) u8 Bs[2][8192];   // 32 KB total
  __shared__ int tokL[128];
  __shared__ float wgtL[128];

  const int tid = threadIdx.x;
  const int lane = tid & 63, w = tid >> 6;
  if (tid < 128) {
    int li = min(tid, rows - 1);
    tokL[tid] = ltok12[base + li];
    wgtL[tid] = lwgt12[base + li];
  }
  __syncthreads();

  // staging: linear LDS (slot s = i*256+tid -> row=s>>2, 16B-chunk=s&3);
  // source column pre-swizzled: chunk ^ ((row>>1)&3)  [16B granularity]
  const int srcSwz = (((tid & 3) ^ ((tid >> 3) & 3)) * 16);
  const u8* aSrc[2]; const u8* bSrc[2];
#pragma unroll
  for (int i = 0; i < 2; ++i) {
    int r = i * 64 + (tid >> 2);
    aSrc[i] = A + (size_t)tokL[min(r, rows - 1)] * KB + srcSwz;
    bSrc[i] = W + ((size_t)e * NOUT + ntile * 128 + r) * KB + srcSwz;
  }

  f32x4 acc[4][4] = {};
  const int wr = w >> 1, wc = w & 1;          // 2x2 wave grid, per-wave 64x64
  // read-side swizzle: frag bytes (lane>>4)*8 + kk*32 -> chunk=(lane>>5)|(kk<<1), parity=(lane>>4)&1
  const int sxr = (lane >> 1) & 3;
  const int p8 = ((lane >> 4) & 1) * 8;
  const int roff0 = 16 * (((lane >> 5) | 0) ^ sxr) + p8;
  const int roff1 = 16 * (((lane >> 5) | 2) ^ sxr) + p8;
  constexpr int NT = KB / 64;

#define STAGE(kt_) do { int ko_ = (kt_) * 64; int b_ = (kt_) & 1;               \
    async16(aSrc[0] + ko_, &As[b_][tid * 16]);                                  \
    async16(aSrc[1] + ko_, &As[b_][(256 + tid) * 16]);                          \
    async16(bSrc[0] + ko_, &Bs[b_][tid * 16]);                                  \
    async16(bSrc[1] + ko_, &Bs[b_][(256 + tid) * 16]); } while (0)

  STAGE(0);
  __syncthreads();
  for (int kt = 0; kt < NT; ++kt) {
    if (kt + 1 < NT) STAGE(kt + 1);          // lands under compute; drained by end-sync
    const u8* Ab = &As[kt & 1][0];
    const u8* Bb = &Bs[kt & 1][0];
#pragma unroll
    for (int kk = 0; kk < 2; ++kk) {
      const int ro = kk ? roff1 : roff0;
      long bf[4];
#pragma unroll
      for (int ni = 0; ni < 4; ++ni) {
        int rB = wc * 64 + ni * 16 + (lane & 15);
        bf[ni] = *(const long*)&Bb[rB * 64 + ro];
      }
#pragma unroll
      for (int mi = 0; mi < 4; ++mi) {
        int rA = wr * 64 + mi * 16 + (lane & 15);
        long af = *(const long*)&Ab[rA * 64 + ro];
#pragma unroll
        for (int ni = 0; ni < 4; ++ni)
          acc[mi][ni] = __builtin_amdgcn_mfma_f32_16x16x32_fp8_fp8(af, bf[ni], acc[mi][ni], 0, 0, 0);
      }
    }
    __syncthreads();
  }
#undef STAGE

  // epilogue: scaled scatter (RMW; bf16 pair-packed u32, f32 scalar)
#pragma unroll
  for (int mi = 0; mi < 4; ++mi) {
    int lr0 = wr * 64 + mi * 16 + ((lane >> 4) << 2);
#pragma unroll
    for (int rr = 0; rr < 4; ++rr) {
      int lrow = lr0 + rr;
      bool rowok = lrow < rows;
      int tok = tokL[lrow];
      float wv = wgtL[lrow] * outScale;
      if constexpr (sizeof(CT) == 2) {
        u32* cp32 = (u32*)((u16*)C + (size_t)tok * NOUT + ntile * 128 + wc * 64 + (lane & 14));
#pragma unroll
        for (int ni = 0; ni < 4; ++ni) {
          float v = acc[mi][ni][rr] * wv;
          float vo = __shfl_xor(v, 1);
          if (rowok && !(lane & 1)) {
            float lo = v, hi = vo;
            if (ADD) {
              u32 curv = cp32[ni * 8];
              lo += b2f((u16)(curv & 0xffffu));
              hi += b2f((u16)(curv >> 16));
            }
            cp32[ni * 8] = (u32)f2b(lo) | ((u32)f2b(hi) << 16);
          }
        }
      } else {
        if (rowok) {
          float* cp = (float*)C + (size_t)tok * NOUT + ntile * 128 + wc * 64 + (lane & 15);
#pragma unroll
          for (int ni = 0; ni < 4; ++ni) {
            float val = acc[mi][ni][rr] * wv;
            float* p = cp + ni * 16;
            *p = ADD ? (*p + val) : val;
          }
        }
      }
    }
  }
}

// ---------------- exact GELU on bf16 h -> fp8 (x256) h8 ----------------
DEVI float gelu1(float v) { return 0.5f * v * (1.0f + erff(v * 0.70710678118654752f)); }
__global__ void gelu8_k(const u32* __restrict__ h, uint2* __restrict__ h8, long n8) {
  // n8 = elem count / 8; each thread: 8 bf16 in (16B), 8 fp8 out (8B)
  long stride = (long)gridDim.x * blockDim.x;
  const uint4* hp = (const uint4*)h;
  for (long i = (long)blockIdx.x * blockDim.x + threadIdx.x; i < n8; i += stride) {
    uint4 v = hp[i];
    u32 words[4] = { v.x, v.y, v.z, v.w };
    u32 lo = 0, hi = 0;
#pragma unroll
    for (int j = 0; j < 4; ++j) {
      float f0 = b2f((u16)(words[j] & 0xffffu));
      float f1 = b2f((u16)(words[j] >> 16));
      u32 c0 = f2fp8(gelu1(f0) * 256.f);
      u32 c1 = f2fp8(gelu1(f1) * 256.f);
      u32 pair = c0 | (c1 << 8);
      if (j < 2) lo |= pair << (16 * j);
      else       hi |= pair << (16 * (j - 2));
    }
    h8[i] = make_uint2(lo, hi);
  }
}

extern "C" void kernel_launch(void* const* d_in, const int* in_sizes, int n_in,
                              void* d_out, int out_size, void* d_ws, size_t ws_size,
                              hipStream_t stream) {
  const float* x  = (const float*)d_in[0];
  const float* Pw = (const float*)d_in[1];
  const float* U1 = (const float*)d_in[2];
  const float* U2 = (const float*)d_in[3];
  const float* U3 = (const float*)d_in[4];
  const float* W1 = (const float*)d_in[5];
  const float* W2 = (const float*)d_in[6];
  const float* b2 = (const float*)d_in[7];
  float* out = (float*)d_out;

  char* ws = (char*)d_ws;
  size_t o = 0;
  u8*  W1b = (u8*)(ws + o); o += (size_t)12 * 4096 * 1024;   // fp8 W1 (x1024)
  u8*  W2b = (u8*)(ws + o); o += (size_t)12 * 1024 * 4096;   // fp8 W2 (x1024)
  u8*  xb  = (u8*)(ws + o); o += (size_t)8192 * 1024;        // fp8 x
  u16* h   = (u16*)(ws + o); o += (size_t)8192 * 4096 * 2;   // bf16 h accumulate
  u8*  h8  = (u8*)(ws + o); o += (size_t)8192 * 4096;        // fp8 gelu(h) (x256)
  int* cnt = (int*)(ws + o); o += 512;
  int2* desc = (int2*)(ws + o); o += (size_t)6 * 96 * sizeof(int2);
  o = (o + 255) & ~(size_t)255;
  int* ntl = (int*)(ws + o); o += 256;
  int* ltok = (int*)(ws + o); o += (size_t)6 * 12 * CAP * 4;
  float* lwgt = (float*)(ws + o); o += (size_t)6 * 12 * CAP * 4;
  if (ws_size < o) return;

  hipMemsetAsync(cnt, 0, 512, stream);
  cvt8_k<<<4096, 256, 0, stream>>>(W1, W1b, W2, W2b, (long)12 * 4096 * 1024);
  xrouter_k<<<1024, 256, 0, stream>>>(x, Pw, U1, U2, U3, b2, cnt, ltok, lwgt, out, xb);
  build_k<<<1, 64, 0, stream>>>(cnt, desc, ntl);

  const float s1 = 1.0f / 1024.f;            // undo W1 scale
  const float s2 = 1.0f / (1024.f * 256.f);  // undo W2 and h scales

  { // layer 1: h = sum over ranks of w * (x @ W1[e]^T)   (bf16 RMW in ws)
    dim3 g(80, 32);
    int s;
    s = 0; moe_gemm<1024, 4096, false, u16><<<g, 256, 0, stream>>>(xb, W1b, h, s1, cnt + s * 12, ltok + (size_t)s * 12 * CAP, lwgt + (size_t)s * 12 * CAP, desc + s * 96, ntl + s);
    s = 1; moe_gemm<1024, 4096, true , u16><<<g, 256, 0, stream>>>(xb, W1b, h, s1, cnt + s * 12, ltok + (size_t)s * 12 * CAP, lwgt + (size_t)s * 12 * CAP, desc + s * 96, ntl + s);
    s = 2; moe_gemm<1024, 4096, true , u16><<<g, 256, 0, stream>>>(xb, W1b, h, s1, cnt + s * 12, ltok + (size_t)s * 12 * CAP, lwgt + (size_t)s * 12 * CAP, desc + s * 96, ntl + s);
  }

  gelu8_k<<<2048, 256, 0, stream>>>((const u32*)h, (uint2*)h8, (long)8192 * 4096 / 8);

  { // layer 2: out += sum over ranks of w * (gelu(h) @ W2[e]^T)   (bias already in out, f32)
    dim3 g(80, 8);
    int s;
    s = 3; moe_gemm<4096, 1024, true, float><<<g, 256, 0, stream>>>(h8, W2b, out, s2, cnt + s * 12, ltok + (size_t)s * 12 * CAP, lwgt + (size_t)s * 12 * CAP, desc + s * 96, ntl + s);
    s = 4; moe_gemm<4096, 1024, true, float><<<g, 256, 0, stream>>>(h8, W2b, out, s2, cnt + s * 12, ltok + (size_t)s * 12 * CAP, lwgt + (size_t)s * 12 * CAP, desc + s * 96, ntl + s);
    s = 5; moe_gemm<4096, 1024, true, float><<<g, 256, 0, stream>>>(h8, W2b, out, s2, cnt + s * 12, ltok + (size_t)s * 12 * CAP, lwgt + (size_t)s * 12 * CAP, desc + s * 96, ntl + s);
  }
}